// Round 1
// baseline (7482.112 us; speedup 1.0000x reference)
//
#include <hip/hip_runtime.h>

// Mamba selective scan, scalar state per channel.
//   a_t = exp(delta_t * A_d);  h_t = a_t*h_{t-1} + delta_t*B_t*u_t;  y_t = C_t*h_t
// Single-pass decoupled-lookback chunked scan: inputs read exactly once.
// 8192 independent (batch,channel) scans of length 4096; chunk T=16 steps.

#define BB 8
#define SS 4096
#define DD 1024
#define TT 16
#define NCHUNK (SS / TT)        // 256 chunks along seq
#define NGROUP (DD / 256)       // 4 channel-groups of 256
#define NBLK (BB * NGROUP * NCHUNK)  // 8192 blocks

__global__ __launch_bounds__(256) void mamba_scan_kernel(
    const float* __restrict__ u, const float* __restrict__ delta,
    const float* __restrict__ A, const float* __restrict__ Bm,
    const float* __restrict__ Cm, float* __restrict__ out,
    float* __restrict__ aggA, float* __restrict__ aggB,
    float* __restrict__ incB, int* __restrict__ flags)
{
    const int bid = blockIdx.x;
    const int tid = threadIdx.x;
    const int c  = bid % NCHUNK;        // chunk index (fastest-varying -> preds have lower bid)
    const int bg = bid / NCHUNK;
    const int g  = bg % NGROUP;
    const int b  = bg / NGROUP;
    const int d  = (g << 8) + tid;      // channel

    const float Ad = A[d];
    const size_t base = ((size_t)(b * SS + c * TT)) * DD + (size_t)d;

    // Phase 1: local inclusive scan of this chunk (h_init = 0), fully unrolled
    // so hl[]/pa[] stay in registers (runtime indexing would spill to scratch).
    float hl[TT], pa[TT];
    float h = 0.0f, p = 1.0f;
#pragma unroll
    for (int t = 0; t < TT; ++t) {
        const size_t idx = base + (size_t)t * DD;
        const float dt = delta[idx];
        const float bv = Bm[idx];
        const float uv = u[idx];
        const float a  = __expf(dt * Ad);
        const float x  = dt * bv * uv;
        h = fmaf(a, h, x);
        p *= a;
        hl[t] = h;
        pa[t] = p;
    }

    const int vidx = bid * 256 + tid;
    float X;  // h_init = state at end of previous chunk
    if (c == 0) {
        X = 0.0f;
    } else {
        // Publish chunk aggregate (per-channel), then flag=1 at agent scope.
        aggA[vidx] = p;
        aggB[vidx] = h;
        __threadfence();
        __syncthreads();
        if (tid == 0)
            __hip_atomic_store(&flags[bid], 1, __ATOMIC_RELEASE, __HIP_MEMORY_SCOPE_AGENT);

        // Per-thread decoupled lookback (each thread owns one channel; any mix
        // of aggregate/inclusive reads composes to the exact same value).
        float curA = 1.0f, curB = 0.0f;
        int pch = c - 1;
        int pb  = bid - 1;
        while (true) {
            if (pch < 0) { X = curB; break; }
            int f;
            do {
                f = __hip_atomic_load(&flags[pb], __ATOMIC_ACQUIRE, __HIP_MEMORY_SCOPE_AGENT);
            } while (f == 0);
            const int pv = pb * 256 + tid;
            if (f == 2) { X = fmaf(curA, incB[pv], curB); break; }
            curB = fmaf(curA, aggB[pv], curB);
            curA *= aggA[pv];
            --pch; --pb;
        }
    }

    // Publish inclusive state for successors.
    incB[vidx] = fmaf(p, X, h);
    __threadfence();
    __syncthreads();
    if (tid == 0)
        __hip_atomic_store(&flags[bid], 2, __ATOMIC_RELEASE, __HIP_MEMORY_SCOPE_AGENT);

    // Phase 3: y_t = C_t * (hl[t] + pa[t] * h_init)  (independent per t)
#pragma unroll
    for (int t = 0; t < TT; ++t) {
        const size_t idx = base + (size_t)t * DD;
        const float cv = Cm[idx];
        out[idx] = cv * fmaf(pa[t], X, hl[t]);
    }
}

extern "C" void kernel_launch(void* const* d_in, const int* in_sizes, int n_in,
                              void* d_out, int out_size, void* d_ws, size_t ws_size,
                              hipStream_t stream) {
    (void)in_sizes; (void)n_in; (void)out_size; (void)ws_size;
    const float* u     = (const float*)d_in[0];
    const float* delta = (const float*)d_in[1];
    const float* A     = (const float*)d_in[2];
    const float* Bm    = (const float*)d_in[3];
    const float* Cm    = (const float*)d_in[4];
    float* out = (float*)d_out;

    float* ws = (float*)d_ws;
    const size_t n = (size_t)NBLK * 256;
    float* aggA = ws;
    float* aggB = ws + n;
    float* incB = ws + 2 * n;
    int*   flags = (int*)(ws + 3 * n);

    // Reset lookback flags every launch (graph replays reuse ws without re-poison).
    hipMemsetAsync(flags, 0, NBLK * sizeof(int), stream);

    mamba_scan_kernel<<<NBLK, 256, 0, stream>>>(u, delta, A, Bm, Cm, out,
                                                aggA, aggB, incB, flags);
}

// Round 2
// 268.036 us; speedup vs baseline: 27.9145x; 27.9145x over previous
//
#include <hip/hip_runtime.h>

// Mamba selective scan: h_t = exp(delta_t*A)*h_{t-1} + delta_t*B_t*u_t ; y_t = C_t*h_t
// 3-pass hierarchical scan (no atomics / no inter-block spin):
//   K1: per-chunk local scan -> chunk aggregates (p = prod a, h = local end state)
//   K2: per-chain wave shuffle-scan of chunk aggregates -> exclusive prefixes (in place)
//   K3: recompute local scan seeded with prefix, y = C*h.
// Each thread owns 4 consecutive channels -> all global traffic is float4.

#define BB 8
#define SS 4096
#define DD 1024
#define TT 16
#define NCHUNK (SS / TT)          // 256 chunks per chain
#define NBLK   (BB * NCHUNK)      // 2048 blocks, 256 thr (thread = 4 channels)

__global__ __launch_bounds__(256) void k1_local(
    const float* __restrict__ u, const float* __restrict__ delta,
    const float* __restrict__ A, const float* __restrict__ Bm,
    float* __restrict__ aggA, float* __restrict__ aggB)
{
    const int c = blockIdx.x % NCHUNK;
    const int b = blockIdx.x / NCHUNK;
    const int d4 = threadIdx.x << 2;

    const float4 Av = *(const float4*)(A + d4);
    size_t idx = ((size_t)(b * SS + c * TT)) * DD + d4;

    float4 h = {0.f, 0.f, 0.f, 0.f};
    float4 p = {1.f, 1.f, 1.f, 1.f};
#pragma unroll 4
    for (int t = 0; t < TT; ++t, idx += DD) {
        const float4 dt = *(const float4*)(delta + idx);
        const float4 bv = *(const float4*)(Bm + idx);
        const float4 uv = *(const float4*)(u + idx);
        float a;
        a = __expf(dt.x * Av.x); h.x = fmaf(a, h.x, dt.x * bv.x * uv.x); p.x *= a;
        a = __expf(dt.y * Av.y); h.y = fmaf(a, h.y, dt.y * bv.y * uv.y); p.y *= a;
        a = __expf(dt.z * Av.z); h.z = fmaf(a, h.z, dt.z * bv.z * uv.z); p.z *= a;
        a = __expf(dt.w * Av.w); h.w = fmaf(a, h.w, dt.w * bv.w * uv.w); p.w *= a;
    }
    const size_t o = ((size_t)(b * NCHUNK + c)) * DD + d4;
    *(float4*)(aggA + o) = p;
    *(float4*)(aggB + o) = h;
}

// One wave per chain (b,d). Lane L owns chunks 4L..4L+3. Inclusive shuffle-scan
// of (a,b) segment composition, then exclusive prefixes written back into aggB.
__global__ __launch_bounds__(256) void k2_scan(
    const float* __restrict__ aggA, float* __restrict__ aggB)
{
    const int chain = blockIdx.x * 4 + (threadIdx.x >> 6);   // 0..8191
    const int lane  = threadIdx.x & 63;
    const int b = chain >> 10;
    const int d = chain & 1023;
    const size_t base = (size_t)b * NCHUNK * DD + (size_t)d;
    const int c0 = lane << 2;

    float a0, a1, a2, a3, b0, b1, b2, b3;
    {
        size_t o = base + (size_t)c0 * DD;
        a0 = aggA[o]; b0 = aggB[o]; o += DD;
        a1 = aggA[o]; b1 = aggB[o]; o += DD;
        a2 = aggA[o]; b2 = aggB[o]; o += DD;
        a3 = aggA[o]; b3 = aggB[o];
    }
    // segment composition: (P then Q) = (Pa*Qa, Qa*Pb + Qb)
    const float A01 = a0 * a1, B01 = fmaf(a1, b0, b1);
    const float A23 = a2 * a3, B23 = fmaf(a3, b2, b3);
    float Aa = A01 * A23;
    float Bb = fmaf(A23, B01, B23);
#pragma unroll
    for (int s = 1; s < 64; s <<= 1) {
        const float Ap = __shfl_up(Aa, s);
        const float Bp = __shfl_up(Bb, s);
        if (lane >= s) { Bb = fmaf(Aa, Bp, Bb); Aa *= Ap; }
    }
    float X0 = __shfl_up(Bb, 1);
    if (lane == 0) X0 = 0.0f;
    const float X1 = fmaf(a0, X0, b0);
    const float X2 = fmaf(a1, X1, b1);
    const float X3 = fmaf(a2, X2, b2);
    size_t o = base + (size_t)c0 * DD;
    aggB[o] = X0; o += DD;
    aggB[o] = X1; o += DD;
    aggB[o] = X2; o += DD;
    aggB[o] = X3;
}

__global__ __launch_bounds__(256) void k3_apply(
    const float* __restrict__ u, const float* __restrict__ delta,
    const float* __restrict__ A, const float* __restrict__ Bm,
    const float* __restrict__ Cm, const float* __restrict__ pref,
    float* __restrict__ out)
{
    const int c = blockIdx.x % NCHUNK;
    const int b = blockIdx.x / NCHUNK;
    const int d4 = threadIdx.x << 2;

    const float4 Av = *(const float4*)(A + d4);
    float4 h = *(const float4*)(pref + ((size_t)(b * NCHUNK + c)) * DD + d4);

    size_t idx = ((size_t)(b * SS + c * TT)) * DD + d4;
#pragma unroll 4
    for (int t = 0; t < TT; ++t, idx += DD) {
        const float4 dt = *(const float4*)(delta + idx);
        const float4 bv = *(const float4*)(Bm + idx);
        const float4 uv = *(const float4*)(u + idx);
        const float4 cv = *(const float4*)(Cm + idx);
        float a; float4 y;
        a = __expf(dt.x * Av.x); h.x = fmaf(a, h.x, dt.x * bv.x * uv.x); y.x = cv.x * h.x;
        a = __expf(dt.y * Av.y); h.y = fmaf(a, h.y, dt.y * bv.y * uv.y); y.y = cv.y * h.y;
        a = __expf(dt.z * Av.z); h.z = fmaf(a, h.z, dt.z * bv.z * uv.z); y.z = cv.z * h.z;
        a = __expf(dt.w * Av.w); h.w = fmaf(a, h.w, dt.w * bv.w * uv.w); y.w = cv.w * h.w;
        *(float4*)(out + idx) = y;
    }
}

extern "C" void kernel_launch(void* const* d_in, const int* in_sizes, int n_in,
                              void* d_out, int out_size, void* d_ws, size_t ws_size,
                              hipStream_t stream) {
    (void)in_sizes; (void)n_in; (void)out_size; (void)ws_size;
    const float* u     = (const float*)d_in[0];
    const float* delta = (const float*)d_in[1];
    const float* A     = (const float*)d_in[2];
    const float* Bm    = (const float*)d_in[3];
    const float* Cm    = (const float*)d_in[4];
    float* out = (float*)d_out;

    float* ws = (float*)d_ws;
    const size_t n = (size_t)BB * NCHUNK * DD;   // 2M floats = 8 MB
    float* aggA = ws;
    float* aggB = ws + n;

    k1_local<<<NBLK, 256, 0, stream>>>(u, delta, A, Bm, aggA, aggB);
    k2_scan<<<BB * DD / 4, 256, 0, stream>>>(aggA, aggB);
    k3_apply<<<NBLK, 256, 0, stream>>>(u, delta, A, Bm, Cm, aggB, out);
}

// Round 4
// 244.755 us; speedup vs baseline: 30.5698x; 1.0951x over previous
//
#include <hip/hip_runtime.h>

// Mamba selective scan: h_t = exp(delta_t*A)*h_{t-1} + delta_t*B_t*u_t ; y_t = C_t*h_t
// 3-pass hierarchical scan. Round-4: same as round-3 (depth-2 software-pipelined
// loads in K1/K3, coalesced sequential K2, nontemporal y stores) with the
// nontemporal store fixed to use a clang ext_vector type (HIP_vector_type
// float4 is rejected by __builtin_nontemporal_store).

#define BB 8
#define SS 4096
#define DD 1024
#define TT 16
#define NCHUNK (SS / TT)          // 256 chunks per chain
#define NBLK   (BB * NCHUNK)      // 2048 blocks, 256 thr (thread = 4 channels)

typedef __attribute__((ext_vector_type(4))) float f32x4;

__device__ __forceinline__ float4 ld4(const float* __restrict__ p) {
    return *(const float4*)p;
}

__device__ __forceinline__ void scan_step(float4& h, float4& p,
                                          const float4 dt, const float4 bv,
                                          const float4 uv, const float4 Av) {
    float a;
    a = __expf(dt.x * Av.x); h.x = fmaf(a, h.x, dt.x * bv.x * uv.x); p.x *= a;
    a = __expf(dt.y * Av.y); h.y = fmaf(a, h.y, dt.y * bv.y * uv.y); p.y *= a;
    a = __expf(dt.z * Av.z); h.z = fmaf(a, h.z, dt.z * bv.z * uv.z); p.z *= a;
    a = __expf(dt.w * Av.w); h.w = fmaf(a, h.w, dt.w * bv.w * uv.w); p.w *= a;
}

__global__ __launch_bounds__(256) void k1_local(
    const float* __restrict__ u, const float* __restrict__ delta,
    const float* __restrict__ A, const float* __restrict__ Bm,
    float* __restrict__ aggA, float* __restrict__ aggB)
{
    const int c = blockIdx.x % NCHUNK;
    const int b = blockIdx.x / NCHUNK;
    const int d4 = threadIdx.x << 2;

    const float4 Av = ld4(A + d4);
    const size_t base = ((size_t)(b * SS + c * TT)) * DD + d4;

    float4 h = {0.f, 0.f, 0.f, 0.f};
    float4 p = {1.f, 1.f, 1.f, 1.f};

    // depth-2 pipeline: stages t, t+1, t+2 live; ring index is compile-time
    // constant after full unroll (rule #20).
    float4 dt[3], bv[3], uv[3];
    dt[0] = ld4(delta + base);      bv[0] = ld4(Bm + base);      uv[0] = ld4(u + base);
    dt[1] = ld4(delta + base + DD); bv[1] = ld4(Bm + base + DD); uv[1] = ld4(u + base + DD);
#pragma unroll
    for (int t = 0; t < TT; ++t) {
        if (t + 2 < TT) {
            const int s2 = (t + 2) % 3;
            const size_t i2 = base + (size_t)(t + 2) * DD;
            dt[s2] = ld4(delta + i2);
            bv[s2] = ld4(Bm + i2);
            uv[s2] = ld4(u + i2);
        }
        const int s = t % 3;
        scan_step(h, p, dt[s], bv[s], uv[s], Av);
    }
    const size_t o = ((size_t)(b * NCHUNK + c)) * DD + d4;
    *(float4*)(aggA + o) = p;
    *(float4*)(aggB + o) = h;
}

// Thread-per-chain sequential scan of chunk aggregates -> exclusive prefixes.
// Coalesced loads/stores (consecutive d per lane); serial fma chain is only
// ~256 x 6 cyc, loads hoisted ahead by unroll.
__global__ __launch_bounds__(64) void k2_scan(
    const float* __restrict__ aggA, const float* __restrict__ aggB,
    float* __restrict__ pref)
{
    const int b = blockIdx.x >> 4;                          // 8 batches
    const int d = ((blockIdx.x & 15) << 6) + threadIdx.x;   // 16 groups of 64
    const size_t base = (size_t)b * NCHUNK * DD + (size_t)d;

    float X = 0.f;
#pragma unroll 8
    for (int c = 0; c < NCHUNK; ++c) {
        const size_t o = base + (size_t)c * DD;
        pref[o] = X;
        X = fmaf(aggA[o], X, aggB[o]);
    }
}

__global__ __launch_bounds__(256) void k3_apply(
    const float* __restrict__ u, const float* __restrict__ delta,
    const float* __restrict__ A, const float* __restrict__ Bm,
    const float* __restrict__ Cm, const float* __restrict__ pref,
    float* __restrict__ out)
{
    const int c = blockIdx.x % NCHUNK;
    const int b = blockIdx.x / NCHUNK;
    const int d4 = threadIdx.x << 2;

    const float4 Av = ld4(A + d4);
    float4 h = ld4(pref + ((size_t)(b * NCHUNK + c)) * DD + d4);
    const size_t base = ((size_t)(b * SS + c * TT)) * DD + d4;

    // depth-2 pipeline for scan streams, depth-1 for C.
    float4 dt[3], bv[3], uv[3], cv[2];
    float4 dump = {0.f, 0.f, 0.f, 0.f};   // p-product not needed in K3
    dt[0] = ld4(delta + base);      bv[0] = ld4(Bm + base);      uv[0] = ld4(u + base);
    dt[1] = ld4(delta + base + DD); bv[1] = ld4(Bm + base + DD); uv[1] = ld4(u + base + DD);
    cv[0] = ld4(Cm + base);
#pragma unroll
    for (int t = 0; t < TT; ++t) {
        if (t + 2 < TT) {
            const int s2 = (t + 2) % 3;
            const size_t i2 = base + (size_t)(t + 2) * DD;
            dt[s2] = ld4(delta + i2);
            bv[s2] = ld4(Bm + i2);
            uv[s2] = ld4(u + i2);
        }
        if (t + 1 < TT) cv[(t + 1) % 2] = ld4(Cm + base + (size_t)(t + 1) * DD);
        const int s = t % 3;
        scan_step(h, dump, dt[s], bv[s], uv[s], Av);
        const float4 c4 = cv[t % 2];
        f32x4 y;
        y.x = c4.x * h.x; y.y = c4.y * h.y; y.z = c4.z * h.z; y.w = c4.w * h.w;
        __builtin_nontemporal_store(y, (f32x4*)(out + base + (size_t)t * DD));
    }
}

extern "C" void kernel_launch(void* const* d_in, const int* in_sizes, int n_in,
                              void* d_out, int out_size, void* d_ws, size_t ws_size,
                              hipStream_t stream) {
    (void)in_sizes; (void)n_in; (void)out_size; (void)ws_size;
    const float* u     = (const float*)d_in[0];
    const float* delta = (const float*)d_in[1];
    const float* A     = (const float*)d_in[2];
    const float* Bm    = (const float*)d_in[3];
    const float* Cm    = (const float*)d_in[4];
    float* out = (float*)d_out;

    float* ws = (float*)d_ws;
    const size_t n = (size_t)BB * NCHUNK * DD;   // 2M floats = 8 MB per buffer
    float* aggA = ws;
    float* aggB = ws + n;
    float* pref = ws + 2 * n;

    k1_local<<<NBLK, 256, 0, stream>>>(u, delta, A, Bm, aggA, aggB);
    k2_scan<<<BB * (DD / 64), 64, 0, stream>>>(aggA, aggB, pref);
    k3_apply<<<NBLK, 256, 0, stream>>>(u, delta, A, Bm, Cm, pref, out);
}